// Round 5
// baseline (765.699 us; speedup 1.0000x reference)
//
#include <hip/hip_runtime.h>
#include <hip/hip_fp16.h>

#define N_ROWS 8192
#define K_DIM  4096
#define M_DIM  4096
#define NT     (K_DIM / 64)      // 64 K-tiles of BK=64
#define HT_MAX (4 * NT)          // 256 quarter-tile stage slots

typedef __attribute__((ext_vector_type(8))) _Float16 half8;
typedef __attribute__((ext_vector_type(4))) _Float16 half4v;
typedef __attribute__((ext_vector_type(4))) float    f32x4;

// ---------------------------------------------------------------------------
// Quant: one wave per row: amax -> softplus scale -> int16 fake-quant -> f16.
// ---------------------------------------------------------------------------
__global__ __launch_bounds__(256) void quant_kernel(
    const float* __restrict__ x, _Float16* __restrict__ xq, float* __restrict__ sx)
{
    const int t    = threadIdx.x;
    const int lane = t & 63;
    const int row  = blockIdx.x * 4 + (t >> 6);
    const float4* xr4 = (const float4*)(x + (size_t)row * K_DIM);

    float4 v[16];
    float am = 0.0f;
#pragma unroll
    for (int j = 0; j < 16; ++j) {
        v[j] = xr4[j * 64 + lane];
        am = fmaxf(am, fmaxf(fmaxf(fabsf(v[j].x), fabsf(v[j].y)),
                             fmaxf(fabsf(v[j].z), fabsf(v[j].w))));
    }
#pragma unroll
    for (int off = 32; off; off >>= 1)
        am = fmaxf(am, __shfl_xor(am, off, 64));

    const float sp    = (am > 20.0f) ? am : log1pf(expf(am));  // softplus
    const float scale = sp * (1.0f / 32767.0f);
    const float inv   = 32767.0f / sp;
    if (lane == 0) sx[row] = scale;

    half4v* out4 = (half4v*)(xq + (size_t)row * K_DIM);
#pragma unroll
    for (int j = 0; j < 16; ++j) {
        half4v h;
        h[0] = (_Float16)fminf(fmaxf(rintf(v[j].x * inv), -32768.0f), 32767.0f);
        h[1] = (_Float16)fminf(fmaxf(rintf(v[j].y * inv), -32768.0f), 32767.0f);
        h[2] = (_Float16)fminf(fmaxf(rintf(v[j].z * inv), -32768.0f), 32767.0f);
        h[3] = (_Float16)fminf(fmaxf(rintf(v[j].w * inv), -32768.0f), 32767.0f);
        out4[j * 64 + lane] = h;
    }
}

// ---------------------------------------------------------------------------
// Weight fold: W' = s0*w0 + s1*w1 -> f16. 4 elements per thread.
// ---------------------------------------------------------------------------
__global__ __launch_bounds__(256) void fold_kernel(
    const float* __restrict__ w0, const float* __restrict__ w1,
    const float* __restrict__ s0, const float* __restrict__ s1,
    _Float16* __restrict__ wp)
{
    const size_t gid = (size_t)blockIdx.x * 256 + threadIdx.x;
    const int    o   = (int)(gid >> 10);
    const float  a = s0[o], b = s1[o];

    const float4 u = ((const float4*)w0)[gid];
    const float4 v = ((const float4*)w1)[gid];
    half4v h;
    h[0] = (_Float16)(a * u.x + b * v.x);
    h[1] = (_Float16)(a * u.y + b * v.y);
    h[2] = (_Float16)(a * u.z + b * v.z);
    h[3] = (_Float16)(a * u.w + b * v.w);
    ((half4v*)wp)[gid] = h;
}

// ---------------------------------------------------------------------------
// 256x256 8-phase NT GEMM with REGISTER staging (no global_load_lds).
// Theory (R4 post-mortem): the compiler drains vmcnt(0) before every
// s_barrier when DMA-to-LDS ops are outstanding (LDS-write visibility),
// exposing ~500 cyc HBM latency per phase — the 43% MfmaUtil plateau.
// Reg staging removes the constraint: global_load_dwordx4 -> VGPR (no
// barrier-visibility), ds_write covered by cheap lgkmcnt; the compiler's
// per-register scoreboard emits precise counted vmcnt(2) before each write
// (AITER's never-0 pattern).
// Slot pipeline (slot s = quarter-tile: tile s>>2, part s&3 of
// {A_k0,B_k0,A_k1,B_k1}, LDS region (s>>2)&1):
//   gload  slot s at phase s-5 into gr[s&1]   (2x int4/thread, linear/coalesced)
//   ds_write slot s at phase s-3 from gr[s&1] (swizzled dest: c = pc^((r>>1)&3))
//   read   slot s at phases s-j+{0,1}         (>=1 barrier after write)
// Region WAR: write is >=4 phases after the region's last read. Parity: write
// slot p+3 and gload slot p+5 share gr[(p+3)&1] — write frees, gload refills.
// Phase: [frag ds_reads G_p] [ds_write p+3] [gload p+5] barrier lgkm(0)
//        setprio(1) 16 MFMA setprio(0) barrier.
// ---------------------------------------------------------------------------

#define PH(P)                                                                 \
    {                                                                         \
        constexpr int BUF = (P) >> 2;                                         \
        constexpr int KS  = ((P) >> 1) & 1;                                   \
        constexpr int MH  = (P) & 1;                                          \
        constexpr int PAR = ((P) + 3) & 1;                                    \
        constexpr int WPRT = ((P) + 3) & 3;                                   \
        constexpr int WISB = WPRT & 1;                                        \
        constexpr int WKS  = WPRT >> 1;                                       \
        constexpr int WBUF = (((P) + 3) >> 2) & 1;                            \
        constexpr int GPRT = ((P) + 5) & 3;                                   \
        constexpr int GISB = GPRT & 1;                                        \
        constexpr int GKS  = GPRT >> 1;                                       \
        constexpr int GTOF = ((P) + 5) >> 2;                                  \
        if (MH == 0) {                                                        \
            _Pragma("unroll")                                                 \
            for (int j = 0; j < 4; ++j) {                                     \
                const int r = wn * 64 + j * 16 + fr;                          \
                const int c = fg ^ ((r >> 1) & 3);                            \
                bf[j] = *(const half8*)&Bs[BUF][KS * 8192 + r * 32 + c * 8];  \
            }                                                                 \
        }                                                                     \
        _Pragma("unroll")                                                     \
        for (int i = 0; i < 4; ++i) {                                         \
            const int r = wm * 128 + MH * 64 + i * 16 + fr;                   \
            const int c = fg ^ ((r >> 1) & 3);                                \
            af[i] = *(const half8*)&As[BUF][KS * 8192 + r * 32 + c * 8];      \
        }                                                                     \
        if (it * 8 + (P) + 3 < HT_MAX) {                                      \
            _Float16* lb = (WISB ? &Bs[WBUF][0] : &As[WBUF][0]) + WKS * 8192; \
            _Pragma("unroll")                                                 \
            for (int l = 0; l < 2; ++l) {                                     \
                const int sl = l * 512 + t, r = sl >> 2, pc = sl & 3;         \
                const int c = pc ^ ((r >> 1) & 3);                            \
                *(int4*)&lb[r * 32 + c * 8] = gr[PAR][l];                     \
            }                                                                 \
        }                                                                     \
        if (it * 8 + (P) + 5 < HT_MAX) {                                      \
            const _Float16* gb = GISB ? B + (size_t)o0 * K_DIM                \
                                      : A + (size_t)n0 * K_DIM;               \
            const int kof = (it * 2 + GTOF) * 64 + GKS * 32;                  \
            _Pragma("unroll")                                                 \
            for (int l = 0; l < 2; ++l) {                                     \
                const int sl = l * 512 + t, r = sl >> 2, pc = sl & 3;         \
                gr[PAR][l] =                                                  \
                    *(const int4*)&gb[(size_t)r * K_DIM + kof + pc * 8];      \
            }                                                                 \
        }                                                                     \
        asm volatile("" ::: "memory");                                        \
        __builtin_amdgcn_s_barrier();                                         \
        asm volatile("s_waitcnt lgkmcnt(0)" ::: "memory");                    \
        __builtin_amdgcn_sched_barrier(0);                                    \
        __builtin_amdgcn_s_setprio(1);                                        \
        _Pragma("unroll")                                                     \
        for (int i = 0; i < 4; ++i)                                           \
            _Pragma("unroll")                                                 \
            for (int j = 0; j < 4; ++j)                                       \
                acc[MH * 4 + i][j] = __builtin_amdgcn_mfma_f32_16x16x32_f16(  \
                    af[i], bf[j], acc[MH * 4 + i][j], 0, 0, 0);               \
        __builtin_amdgcn_s_setprio(0);                                        \
        asm volatile("" ::: "memory");                                        \
        __builtin_amdgcn_s_barrier();                                         \
        asm volatile("" ::: "memory");                                        \
    }

__global__ __launch_bounds__(512, 2) void gemm_kernel(
    const _Float16* __restrict__ A,   // [N, K]
    const _Float16* __restrict__ B,   // [M, K]
    const float* __restrict__ sx,     // [N]
    const float* __restrict__ bias,   // [M]
    float* __restrict__ out)          // [N, M]
{
    __shared__ __align__(16) _Float16 As[2][16384];   // [buf][ks*8192 + r*32 + c*8]
    __shared__ __align__(16) _Float16 Bs[2][16384];

    const int t    = threadIdx.x;
    const int lane = t & 63;
    const int wave = t >> 6;
    const int wm   = wave >> 2;       // 0..1  (M half of block)
    const int wn   = wave & 3;        // 0..3  (N quarter of block)

    // XCD-aware swizzle then 8x8 supertile over the 32(n) x 16(m) tile grid.
    const int b2  = (blockIdx.x & 7) * 64 + (blockIdx.x >> 3);
    const int sup = b2 >> 6;
    const int loc = b2 & 63;
    const int tm  = (sup & 1) * 8 + (loc & 7);
    const int tn  = (sup >> 1) * 8 + (loc >> 3);
    const int n0  = tn * 256;
    const int o0  = tm * 256;

    const int fr = lane & 15;
    const int fg = lane >> 4;

    f32x4 acc[8][4] = {};
    int4  gr[2][2];

    // ---- prologue ----
    // slots 0 (A_k0), 1 (B_k0), 2 (A_k1) of tile 0: load -> swizzled ds_write
#pragma unroll
    for (int s = 0; s < 3; ++s) {
        const int prt = s;
        const int ks  = prt >> 1;
        const _Float16* gb = (prt & 1) ? B + (size_t)o0 * K_DIM
                                       : A + (size_t)n0 * K_DIM;
        _Float16* lb = ((prt & 1) ? &Bs[0][0] : &As[0][0]) + ks * 8192;
        const int kof = ks * 32;
#pragma unroll
        for (int l = 0; l < 2; ++l) {
            const int sl = l * 512 + t, r = sl >> 2, pc = sl & 3;
            const int c = pc ^ ((r >> 1) & 3);
            int4 v = *(const int4*)&gb[(size_t)r * K_DIM + kof + pc * 8];
            *(int4*)&lb[r * 32 + c * 8] = v;
        }
    }
    // preload slot 3 (B_k1 tile0) -> gr[1], slot 4 (A_k0 tile1) -> gr[0]
#pragma unroll
    for (int l = 0; l < 2; ++l) {
        const int sl = l * 512 + t, r = sl >> 2, pc = sl & 3;
        gr[1][l] = *(const int4*)&B[(size_t)(o0 + r) * K_DIM + 32 + pc * 8];
        gr[0][l] = *(const int4*)&A[(size_t)(n0 + r) * K_DIM + 64 + pc * 8];
    }
    asm volatile("s_waitcnt lgkmcnt(0)" ::: "memory");
    __builtin_amdgcn_s_barrier();
    asm volatile("" ::: "memory");

    half8 af[4], bf[4];
#pragma unroll 1
    for (int it = 0; it < NT / 2; ++it) {
        PH(0) PH(1) PH(2) PH(3) PH(4) PH(5) PH(6) PH(7)
    }

    // epilogue: C/D layout col = lane&15 (o), row = (lane>>4)*4 + reg (n)
    float bs[4];
#pragma unroll
    for (int j = 0; j < 4; ++j)
        bs[j] = bias[o0 + wn * 64 + j * 16 + fr];
#pragma unroll
    for (int i = 0; i < 8; ++i) {
        const int nb = n0 + wm * 128 + i * 16 + fg * 4;
#pragma unroll
        for (int r = 0; r < 4; ++r) {
            const float s = sx[nb + r];
            float* orow = out + (size_t)(nb + r) * M_DIM;
#pragma unroll
            for (int j = 0; j < 4; ++j)
                orow[o0 + wn * 64 + j * 16 + fr] = acc[i][j][r] * s + bs[j];
        }
    }
}

// ---------------------------------------------------------------------------
extern "C" void kernel_launch(void* const* d_in, const int* in_sizes, int n_in,
                              void* d_out, int out_size, void* d_ws, size_t ws_size,
                              hipStream_t stream)
{
    const float* x    = (const float*)d_in[0];
    const float* w0   = (const float*)d_in[1];
    const float* w1   = (const float*)d_in[2];
    const float* s0   = (const float*)d_in[3];
    const float* s1   = (const float*)d_in[4];
    const float* bias = (const float*)d_in[5];
    float* out = (float*)d_out;

    char* ws = (char*)d_ws;
    _Float16* xq = (_Float16*)ws;                                   // 64 MiB
    _Float16* wp = (_Float16*)(ws + (size_t)N_ROWS * K_DIM * 2);    // 32 MiB
    float*    sx = (float*)(ws + (size_t)N_ROWS * K_DIM * 2
                               + (size_t)M_DIM * K_DIM * 2);        // 32 KiB

    quant_kernel<<<N_ROWS / 4, 256, 0, stream>>>(x, xq, sx);
    fold_kernel<<<(M_DIM * K_DIM) / (256 * 4), 256, 0, stream>>>(w0, w1, s0, s1, wp);

    gemm_kernel<<<(N_ROWS / 256) * (M_DIM / 256), 512, 0, stream>>>(
        xq, wp, sx, bias, out);
}